// Round 8
// baseline (497.742 us; speedup 1.0000x reference)
//
#include <hip/hip_runtime.h>
#include <hip/hip_bf16.h>

#define SEQ 2048
#define NHEADS 8
#define ROWS 8192
#define NBLK 512

typedef __attribute__((ext_vector_type(8))) short bf16x8;
typedef __attribute__((ext_vector_type(4))) short bf16x4;
typedef __attribute__((ext_vector_type(4))) float f32x4;

// workspace layout (offsets in shorts)
#define XB_OFF   0u
#define CB_OFF   (XB_OFF + ROWS * 256)          // 2097152
#define WQ_OFF   (CB_OFF + ROWS * 256)          // 4194304
#define WKV_OFF  (WQ_OFF + 512 * 256)           // 4325376
#define WO_OFF   (WKV_OFF + 1024 * 256)         // 4587520
#define Q2_OFF   (WO_OFF + 256 * 512)           // 4718592
#define KV_OFF   (Q2_OFF + (size_t)ROWS * 512)  // 8912896
#define OB_OFF   (KV_OFF + (size_t)ROWS * 1024) // 17301504
#define CNT_BYTES ((size_t)(OB_OFF + (size_t)ROWS * 512) * 2)  // 42991616

__device__ inline short f2bf(float x) {
    union { float f; unsigned u; } v; v.f = x;
    unsigned r = v.u + 0x7FFF + ((v.u >> 16) & 1);
    return (short)(r >> 16);
}

__device__ inline unsigned pack2bf(float a, float b) {
    __hip_bfloat162 h = __float22bfloat162_rn(make_float2(a, b));
    unsigned u; __builtin_memcpy(&u, &h, 4);
    return u;
}

// ---------------------------------------------------------------------------
// Device-scope grid barrier. Safe because all NBLK=512 blocks are co-resident:
// LDS 36864 B -> 4 blocks/CU possible, launch_bounds(256,2) guarantees >=2.
// ---------------------------------------------------------------------------
__device__ inline void gbar(unsigned* cnt, unsigned target) {
    __syncthreads();          // all waves drain vmem (syncthreads implies vmcnt(0))
    __threadfence();          // release: flush L2 so other XCDs can see our writes
    if (threadIdx.x == 0) {
        atomicAdd(cnt, 1u);
        while (atomicAdd(cnt, 0u) < target) __builtin_amdgcn_s_sleep(8);
    }
    __syncthreads();
    __threadfence();          // acquire: invalidate caches before reading peers' data
}

// ---------------------------------------------------------------------------
// 64x64-tile bf16 MFMA GEMM tile (one tile per call). BK=64, XOR-swizzled
// unpadded LDS, register prefetch. 4 waves in 2x2, each 32x32.
// ---------------------------------------------------------------------------
template <bool OUT_BF16>
__device__ __forceinline__ void gemm_tile(
    const short* __restrict__ A, const short* __restrict__ W,
    const float* __restrict__ bias, void* __restrict__ outp,
    int K, int Ccols, float scale, int r0, int c0,
    short* As, short* Ws, int tid)
{
    const int w = tid >> 6, lane = tid & 63, low = lane & 15, quad = lane >> 4;
    const int wm = w >> 1, wn = w & 1;
    const int srow = tid >> 2;          // 0..63
    const int sc = (tid & 3) * 2;       // chunk pair {0,2,4,6}

    f32x4 acc[2][2];
#pragma unroll
    for (int mt = 0; mt < 2; ++mt)
#pragma unroll
        for (int nt = 0; nt < 2; ++nt) acc[mt][nt] = (f32x4){0.f, 0.f, 0.f, 0.f};

    bf16x8 pab[2], pwb[2];
    {
        const short* ap = A + (size_t)(r0 + srow) * K + sc * 8;
        const short* wp = W + (size_t)(c0 + srow) * K + sc * 8;
        pab[0] = ((const bf16x8*)ap)[0]; pab[1] = ((const bf16x8*)ap)[1];
        pwb[0] = ((const bf16x8*)wp)[0]; pwb[1] = ((const bf16x8*)wp)[1];
    }

    int k0 = 0;
    for (;;) {
        __syncthreads();
#pragma unroll
        for (int c = 0; c < 2; ++c) {
            const int pc = (sc + c) ^ (srow & 7);
            *(bf16x8*)(&As[srow * 64 + pc * 8]) = pab[c];
            *(bf16x8*)(&Ws[srow * 64 + pc * 8]) = pwb[c];
        }
        __syncthreads();
        const int kn = k0 + 64;
        if (kn < K) {
            const short* ap = A + (size_t)(r0 + srow) * K + kn + sc * 8;
            const short* wp = W + (size_t)(c0 + srow) * K + kn + sc * 8;
            pab[0] = ((const bf16x8*)ap)[0]; pab[1] = ((const bf16x8*)ap)[1];
            pwb[0] = ((const bf16x8*)wp)[0]; pwb[1] = ((const bf16x8*)wp)[1];
        }
#pragma unroll
        for (int kh = 0; kh < 2; ++kh) {
            bf16x8 af[2], bfv[2];
#pragma unroll
            for (int t = 0; t < 2; ++t) {
                const int ra = wm * 32 + t * 16 + low;
                af[t] = *(const bf16x8*)(&As[ra * 64 + ((kh * 4 + quad) ^ (ra & 7)) * 8]);
                const int rb = wn * 32 + t * 16 + low;
                bfv[t] = *(const bf16x8*)(&Ws[rb * 64 + ((kh * 4 + quad) ^ (rb & 7)) * 8]);
            }
#pragma unroll
            for (int mt = 0; mt < 2; ++mt)
#pragma unroll
                for (int nt = 0; nt < 2; ++nt)
                    acc[mt][nt] = __builtin_amdgcn_mfma_f32_16x16x32_bf16(af[mt], bfv[nt], acc[mt][nt], 0, 0, 0);
        }
        k0 = kn;
        if (k0 >= K) break;
    }

#pragma unroll
    for (int nt = 0; nt < 2; ++nt) {
        const int col = c0 + wn * 32 + nt * 16 + low;
        const float bv = bias[col];
#pragma unroll
        for (int mt = 0; mt < 2; ++mt) {
            const size_t rbase = (size_t)(r0 + wm * 32 + mt * 16 + quad * 4);
#pragma unroll
            for (int r = 0; r < 4; ++r) {
                const float val = (acc[mt][nt][r] + bv) * scale;
                if (OUT_BF16) ((short*)outp)[(rbase + r) * Ccols + col] = f2bf(val);
                else          ((float*)outp)[(rbase + r) * Ccols + col] = val;
            }
        }
    }
}

// ---------------------------------------------------------------------------
// Fully fused kernel: P0 cvt -> P1 q/kv GEMM -> P2 attention -> P3 o-GEMM,
// separated by device-scope grid barriers. 512 blocks x 256 threads.
// ---------------------------------------------------------------------------
#define KST 72
#define VST 72
#define PST 72

__global__ __launch_bounds__(256, 2) void fused_all(
    const float* __restrict__ x, const float* __restrict__ ctx,
    const float* __restrict__ Wq, const float* __restrict__ bq,
    const float* __restrict__ Wkv, const float* __restrict__ bkv,
    const float* __restrict__ Wo, const float* __restrict__ bo,
    float* __restrict__ out, short* __restrict__ ws, unsigned* __restrict__ cnt)
{
    __shared__ short smem[18432];   // 36864 B, aliased across phases
    const int tid = threadIdx.x;
    const int bid = blockIdx.x;

    short* xb   = ws + XB_OFF;
    short* cb   = ws + CB_OFF;
    short* wqb  = ws + WQ_OFF;
    short* wkvb = ws + WKV_OFF;
    short* wob  = ws + WO_OFF;
    short* q2b  = ws + Q2_OFF;
    short* kv2b = ws + KV_OFF;
    short* ob   = ws + OB_OFF;

    // ===== Phase 0: fp32 -> bf16 casts (x, ctx, Wq, Wkv, Wo) =====
    {
        int i = bid * 256 + tid;
#pragma unroll
        for (int it = 0; it < 9; ++it, i += NBLK * 256) {
            const float* src; short* dst; int off;
            if (i < 524288)       { src = x;   dst = xb;   off = i; }
            else if (i < 1048576) { src = ctx; dst = cb;   off = i - 524288; }
            else if (i < 1081344) { src = Wq;  dst = wqb;  off = i - 1048576; }
            else if (i < 1146880) { src = Wkv; dst = wkvb; off = i - 1081344; }
            else                  { src = Wo;  dst = wob;  off = i - 1146880; }
            const float4 v = ((const float4*)src)[off];
            uint2 o2;
            o2.x = pack2bf(v.x, v.y);
            o2.y = pack2bf(v.z, v.w);
            *(uint2*)(dst + (size_t)off * 4) = o2;
        }
    }
    gbar(cnt, NBLK);

    // ===== Phase 1: q-GEMM (1024 tiles) + kv-GEMM (2048 tiles) =====
    {
        const float qscale = 0.125f * 1.44269504088896f;  // softmax scale + log2e
        short* As = smem;
        short* Ws = smem + 8192;
#pragma unroll 1
        for (int u = bid; u < 1024; u += NBLK)
            gemm_tile<true>(xb, wqb, bq, q2b, 256, 512, qscale,
                            (u >> 3) * 64, (u & 7) * 64, As, Ws, tid);
#pragma unroll 1
        for (int u = bid; u < 2048; u += NBLK)
            gemm_tile<true>(cb, wkvb, bkv, kv2b, 256, 1024, 1.0f,
                            (u >> 4) * 64, (u & 15) * 64, As, Ws, tid);
    }
    gbar(cnt, 2 * NBLK);

    // ===== Phase 2: attention (512 units, 1/block, R6 internals) =====
    {
        short* Ks = smem;
        short* Vt = smem + 4608;
        const int w = tid >> 6;
        const int lane = tid & 63;
        const int low = lane & 15;
        const int quad = lane >> 4;
        short* pw = smem + 9216 + w * (32 * PST);

        // XCD swizzle decode: all 4 qtiles of (b,h) share bid%8 -> one XCD
        const int h = bid & 7;
        const int rest = bid >> 3;
        const int qtile = rest & 15;
        const int b = rest >> 4;
        const int iq0 = qtile * 128;

        bf16x8 qf[2][2];
#pragma unroll
        for (int qt = 0; qt < 2; ++qt)
#pragma unroll
            for (int kh = 0; kh < 2; ++kh)
                qf[qt][kh] = *(const bf16x8*)(q2b + (size_t)(b * SEQ + iq0 + w * 32 + qt * 16 + low) * 512
                                              + h * 64 + kh * 32 + quad * 8);

        const short* kbase = kv2b + (size_t)(b * SEQ) * 1024 + h * 64;
        const short* vbase = kbase + 512;

        float lsum[2] = {0.f, 0.f};
        f32x4 oacc[2][4];
#pragma unroll
        for (int qt = 0; qt < 2; ++qt)
#pragma unroll
            for (int dt = 0; dt < 4; ++dt) oacc[qt][dt] = (f32x4){0.f, 0.f, 0.f, 0.f};

        const int krow = tid >> 2;
        const int kc = (tid & 3) * 16;
        const int vk4 = (tid & 15) * 4;
        const int vd4 = (tid >> 4) * 4;

        bf16x8 pk0, pk1;
        bf16x4 pv0, pv1, pv2, pv3;
        {
            const short* ksrc = kbase + (size_t)krow * 1024 + kc;
            pk0 = *(const bf16x8*)(ksrc);
            pk1 = *(const bf16x8*)(ksrc + 8);
            const short* vs = vbase + (size_t)vk4 * 1024 + vd4;
            pv0 = *(const bf16x4*)(vs);
            pv1 = *(const bf16x4*)(vs + 1024);
            pv2 = *(const bf16x4*)(vs + 2048);
            pv3 = *(const bf16x4*)(vs + 3072);
        }

        for (int jt = 0; jt < SEQ / 64; ++jt) {
            __syncthreads();
            *(bf16x8*)(&Ks[krow * KST + kc]) = pk0;
            *(bf16x8*)(&Ks[krow * KST + kc + 8]) = pk1;
            {
                bf16x4 c0_, c1_, c2_, c3_;
                c0_[0] = pv0[0]; c0_[1] = pv1[0]; c0_[2] = pv2[0]; c0_[3] = pv3[0];
                c1_[0] = pv0[1]; c1_[1] = pv1[1]; c1_[2] = pv2[1]; c1_[3] = pv3[1];
                c2_[0] = pv0[2]; c2_[1] = pv1[2]; c2_[2] = pv2[2]; c2_[3] = pv3[2];
                c3_[0] = pv0[3]; c3_[1] = pv1[3]; c3_[2] = pv2[3]; c3_[3] = pv3[3];
                *(bf16x4*)(&Vt[(vd4 + 0) * VST + vk4]) = c0_;
                *(bf16x4*)(&Vt[(vd4 + 1) * VST + vk4]) = c1_;
                *(bf16x4*)(&Vt[(vd4 + 2) * VST + vk4]) = c2_;
                *(bf16x4*)(&Vt[(vd4 + 3) * VST + vk4]) = c3_;
            }
            __syncthreads();

            if (jt + 1 < SEQ / 64) {
                const short* ksrc = kbase + (size_t)((jt + 1) * 64 + krow) * 1024 + kc;
                pk0 = *(const bf16x8*)(ksrc);
                pk1 = *(const bf16x8*)(ksrc + 8);
                const short* vs = vbase + (size_t)((jt + 1) * 64 + vk4) * 1024 + vd4;
                pv0 = *(const bf16x4*)(vs);
                pv1 = *(const bf16x4*)(vs + 1024);
                pv2 = *(const bf16x4*)(vs + 2048);
                pv3 = *(const bf16x4*)(vs + 3072);
            }

#pragma unroll
            for (int nt = 0; nt < 4; ++nt) {
                const bf16x8 kf0 = *(const bf16x8*)(&Ks[(nt * 16 + low) * KST + quad * 8]);
                const bf16x8 kf1 = *(const bf16x8*)(&Ks[(nt * 16 + low) * KST + 32 + quad * 8]);
#pragma unroll
                for (int qt = 0; qt < 2; ++qt) {
                    f32x4 s = (f32x4){0.f, 0.f, 0.f, 0.f};
                    s = __builtin_amdgcn_mfma_f32_16x16x32_bf16(kf0, qf[qt][0], s, 0, 0, 0);
                    s = __builtin_amdgcn_mfma_f32_16x16x32_bf16(kf1, qf[qt][1], s, 0, 0, 0);
                    const float p0 = __builtin_amdgcn_exp2f(s[0]);
                    const float p1 = __builtin_amdgcn_exp2f(s[1]);
                    const float p2 = __builtin_amdgcn_exp2f(s[2]);
                    const float p3 = __builtin_amdgcn_exp2f(s[3]);
                    lsum[qt] += (p0 + p1) + (p2 + p3);
                    uint2 u;
                    u.x = pack2bf(p0, p1);
                    u.y = pack2bf(p2, p3);
                    *(uint2*)(&pw[(qt * 16 + low) * PST + nt * 16 + quad * 4]) = u;
                }
            }
            __builtin_amdgcn_wave_barrier();

#pragma unroll
            for (int kb = 0; kb < 2; ++kb) {
                bf16x8 pfr[2];
#pragma unroll
                for (int qt = 0; qt < 2; ++qt)
                    pfr[qt] = *(const bf16x8*)(&pw[(qt * 16 + low) * PST + kb * 32 + quad * 8]);
#pragma unroll
                for (int dt = 0; dt < 4; ++dt) {
                    const bf16x8 vf = *(const bf16x8*)(&Vt[(dt * 16 + low) * VST + kb * 32 + quad * 8]);
                    oacc[0][dt] = __builtin_amdgcn_mfma_f32_16x16x32_bf16(pfr[0], vf, oacc[0][dt], 0, 0, 0);
                    oacc[1][dt] = __builtin_amdgcn_mfma_f32_16x16x32_bf16(pfr[1], vf, oacc[1][dt], 0, 0, 0);
                }
            }
            __builtin_amdgcn_wave_barrier();
        }

#pragma unroll
        for (int qt = 0; qt < 2; ++qt) {
            float lv = lsum[qt];
            lv += __shfl_xor(lv, 16);
            lv += __shfl_xor(lv, 32);
            float linv[4];
#pragma unroll
            for (int r = 0; r < 4; ++r)
                linv[r] = 1.f / __shfl(lv, quad * 4 + r);
            short* obase = ob + (size_t)(b * SEQ + iq0 + w * 32 + qt * 16 + quad * 4) * 512 + h * 64;
#pragma unroll
            for (int r = 0; r < 4; ++r)
#pragma unroll
                for (int dt = 0; dt < 4; ++dt)
                    obase[(size_t)r * 512 + dt * 16 + low] = f2bf(oacc[qt][dt][r] * linv[r]);
        }
    }
    gbar(cnt, 3 * NBLK);

    // ===== Phase 3: o-GEMM (512 tiles, 1/block) =====
    {
        short* As = smem;
        short* Ws = smem + 8192;
        gemm_tile<false>(ob, wob, bo, out, 512, 256, 1.0f,
                         (bid >> 2) * 64, (bid & 3) * 64, As, Ws, tid);
    }
}

// ---------------------------------------------------------------------------
extern "C" void kernel_launch(void* const* d_in, const int* in_sizes, int n_in,
                              void* d_out, int out_size, void* d_ws, size_t ws_size,
                              hipStream_t stream) {
    const float* x   = (const float*)d_in[0];  // (4,2048,256)
    const float* ctx = (const float*)d_in[1];  // (4,2048,256)
    const float* Wq  = (const float*)d_in[2];  // (512,256)
    const float* bq  = (const float*)d_in[3];
    const float* Wkv = (const float*)d_in[4];  // (1024,256)
    const float* bkv = (const float*)d_in[5];
    const float* Wo  = (const float*)d_in[6];  // (256,512)
    const float* bo  = (const float*)d_in[7];
    float* out = (float*)d_out;                // (4,2048,256) fp32

    unsigned* cnt = (unsigned*)((char*)d_ws + CNT_BYTES);
    hipMemsetAsync(cnt, 0, sizeof(unsigned), stream);
    fused_all<<<NBLK, 256, 0, stream>>>(
        x, ctx, Wq, bq, Wkv, bkv, Wo, bo, out, (short*)d_ws, cnt);
}

// Round 9
// 169.830 us; speedup vs baseline: 2.9308x; 2.9308x over previous
//
#include <hip/hip_runtime.h>
#include <hip/hip_bf16.h>

#define NB 4
#define SEQ 2048
#define NHEADS 8
#define ROWS (NB * SEQ)

typedef __attribute__((ext_vector_type(8))) short bf16x8;
typedef __attribute__((ext_vector_type(4))) short bf16x4;
typedef __attribute__((ext_vector_type(4))) float f32x4;
typedef __attribute__((ext_vector_type(16))) float f32x16;

__device__ inline short f2bf(float x) {
    union { float f; unsigned u; } v; v.f = x;
    unsigned r = v.u + 0x7FFF + ((v.u >> 16) & 1);
    return (short)(r >> 16);
}

__device__ inline unsigned pack2bf(float a, float b) {
    __hip_bfloat162 h = __float22bfloat162_rn(make_float2(a, b));
    unsigned u; __builtin_memcpy(&u, &h, 4);
    return u;
}

__device__ inline bf16x8 pack8(float4 a, float4 b) {
    union { unsigned u[4]; bf16x8 v; } r;
    r.u[0] = pack2bf(a.x, a.y);
    r.u[1] = pack2bf(a.z, a.w);
    r.u[2] = pack2bf(b.x, b.y);
    r.u[3] = pack2bf(b.z, b.w);
    return r.v;
}

// combine two packed-bf16 pairs from the two K-halves and scale: bf16 out
__device__ inline unsigned comb2(unsigned w1, unsigned w2, float inv) {
    union { unsigned v; float f; } a, b, c, d;
    a.v = w1 << 16;          b.v = w2 << 16;
    c.v = w1 & 0xffff0000u;  d.v = w2 & 0xffff0000u;
    return pack2bf((a.f + b.f) * inv, (c.f + d.f) * inv);
}

// ---------------------------------------------------------------------------
// fp32 -> bf16 cast for x and ctx (one launch). Unit = 4 elements.
// ---------------------------------------------------------------------------
__global__ __launch_bounds__(256) void cvt_xc(
    const float* __restrict__ x, const float* __restrict__ ctx,
    short* __restrict__ xb, short* __restrict__ cb)
{
    const int i = blockIdx.x * 256 + threadIdx.x;
    const float* src; short* dst; int off;
    if (i < 524288) { src = x;   dst = xb; off = i; }
    else            { src = ctx; dst = cb; off = i - 524288; }
    const float4 v = ((const float4*)src)[off];
    uint2 o2;
    o2.x = pack2bf(v.x, v.y);
    o2.y = pack2bf(v.z, v.w);
    *(uint2*)(dst + (size_t)off * 4) = o2;
}

// ---------------------------------------------------------------------------
// 128x128-tile bf16 MFMA GEMM (kv projection). CVT_W converts fp32 weights
// in-staging. XOR-swizzled unpadded LDS; register prefetch.
// ---------------------------------------------------------------------------
template <bool CVT_W>
__global__ __launch_bounds__(256) void gemm128(
    const short* __restrict__ A, const void* __restrict__ W_,
    const float* __restrict__ bias, short* __restrict__ out,
    int K, int Ccols, float scale)
{
    __shared__ short As[128 * 64];
    __shared__ short Ws[128 * 64];
    const int tid = threadIdx.x;
    const int w = tid >> 6, lane = tid & 63, low = lane & 15, quad = lane >> 4;
    const int wm = w >> 1, wn = w & 1;
    const int rM0 = blockIdx.y * 128, c0 = blockIdx.x * 128;
    const int srow = tid >> 3, sj = tid & 7;

    f32x4 acc[4][4];
#pragma unroll
    for (int mt = 0; mt < 4; ++mt)
#pragma unroll
        for (int nt = 0; nt < 4; ++nt) acc[mt][nt] = (f32x4){0.f, 0.f, 0.f, 0.f};

    float4 pwf[4][2];
    bf16x8 pab[4], pwb[4];

    auto loadA = [&](int c, int k0) {
        const int row = c * 32 + srow;
        pab[c] = *(const bf16x8*)(A + (size_t)(rM0 + row) * K + k0 + sj * 8);
    };
    auto loadW = [&](int c, int k0) {
        const int row = c * 32 + srow;
        if constexpr (CVT_W) {
            const float* p = (const float*)W_ + (size_t)(c0 + row) * K + k0 + sj * 8;
            pwf[c][0] = ((const float4*)p)[0];
            pwf[c][1] = ((const float4*)p)[1];
        } else {
            pwb[c] = *(const bf16x8*)((const short*)W_ + (size_t)(c0 + row) * K + k0 + sj * 8);
        }
    };

#pragma unroll
    for (int c = 0; c < 4; ++c) { loadA(c, 0); loadW(c, 0); }

    int k0 = 0;
    for (;;) {
        __syncthreads();
#pragma unroll
        for (int c = 0; c < 4; ++c) {
            const int row = c * 32 + srow;
            const int pc = sj ^ (row & 7);
            *(bf16x8*)(&As[row * 64 + pc * 8]) = pab[c];
            if constexpr (CVT_W) *(bf16x8*)(&Ws[row * 64 + pc * 8]) = pack8(pwf[c][0], pwf[c][1]);
            else                 *(bf16x8*)(&Ws[row * 64 + pc * 8]) = pwb[c];
        }
        __syncthreads();
        const int kn = k0 + 64;
        if (kn < K) {
#pragma unroll
            for (int c = 0; c < 4; ++c) { loadA(c, kn); loadW(c, kn); }
        }
#pragma unroll
        for (int kh = 0; kh < 2; ++kh) {
            bf16x8 af[4], bfv[4];
#pragma unroll
            for (int t = 0; t < 4; ++t) {
                const int ra = wm * 64 + t * 16 + low;
                af[t] = *(const bf16x8*)(&As[ra * 64 + ((kh * 4 + quad) ^ (ra & 7)) * 8]);
                const int rb = wn * 64 + t * 16 + low;
                bfv[t] = *(const bf16x8*)(&Ws[rb * 64 + ((kh * 4 + quad) ^ (rb & 7)) * 8]);
            }
#pragma unroll
            for (int mt = 0; mt < 4; ++mt)
#pragma unroll
                for (int nt = 0; nt < 4; ++nt)
                    acc[mt][nt] = __builtin_amdgcn_mfma_f32_16x16x32_bf16(af[mt], bfv[nt], acc[mt][nt], 0, 0, 0);
        }
        k0 = kn;
        if (k0 >= K) break;
    }

#pragma unroll
    for (int nt = 0; nt < 4; ++nt) {
        const int col = c0 + wn * 64 + nt * 16 + low;
        const float bv = bias[col];
#pragma unroll
        for (int mt = 0; mt < 4; ++mt) {
            const size_t rbase = (size_t)(rM0 + wm * 64 + mt * 16 + quad * 4);
#pragma unroll
            for (int r = 0; r < 4; ++r)
                out[(rbase + r) * Ccols + col] = f2bf((acc[mt][nt][r] + bv) * scale);
        }
    }
}

// ---------------------------------------------------------------------------
// 64x64-tile bf16 MFMA GEMM (q projection): bf16 A, fp32 W cvt in-staging.
// ---------------------------------------------------------------------------
__global__ __launch_bounds__(256) void gemm64_q(
    const short* __restrict__ A, const float* __restrict__ W,
    const float* __restrict__ bias, short* __restrict__ out,
    int K, int Ccols, float scale)
{
    __shared__ short As[64 * 64];
    __shared__ short Ws[64 * 64];
    const int tid = threadIdx.x;
    const int w = tid >> 6, lane = tid & 63, low = lane & 15, quad = lane >> 4;
    const int wm = w >> 1, wn = w & 1;
    const int r0 = blockIdx.y * 64, c0 = blockIdx.x * 64;
    const int srow = tid >> 2;
    const int sc = (tid & 3) * 2;

    f32x4 acc[2][2];
#pragma unroll
    for (int mt = 0; mt < 2; ++mt)
#pragma unroll
        for (int nt = 0; nt < 2; ++nt) acc[mt][nt] = (f32x4){0.f, 0.f, 0.f, 0.f};

    bf16x8 pab[2];
    float4 pwf[2][2];

    auto loadA = [&](int k0) {
        const short* p = A + (size_t)(r0 + srow) * K + k0 + sc * 8;
        pab[0] = ((const bf16x8*)p)[0];
        pab[1] = ((const bf16x8*)p)[1];
    };
    auto loadW = [&](int k0) {
        const float* p = W + (size_t)(c0 + srow) * K + k0 + sc * 8;
        pwf[0][0] = ((const float4*)p)[0]; pwf[0][1] = ((const float4*)p)[1];
        pwf[1][0] = ((const float4*)p)[2]; pwf[1][1] = ((const float4*)p)[3];
    };

    loadA(0); loadW(0);

    int k0 = 0;
    for (;;) {
        __syncthreads();
#pragma unroll
        for (int c = 0; c < 2; ++c) {
            const int pc = (sc + c) ^ (srow & 7);
            *(bf16x8*)(&As[srow * 64 + pc * 8]) = pab[c];
            *(bf16x8*)(&Ws[srow * 64 + pc * 8]) = pack8(pwf[c][0], pwf[c][1]);
        }
        __syncthreads();
        const int kn = k0 + 64;
        if (kn < K) { loadA(kn); loadW(kn); }
#pragma unroll
        for (int kh = 0; kh < 2; ++kh) {
            bf16x8 af[2], bfv[2];
#pragma unroll
            for (int t = 0; t < 2; ++t) {
                const int ra = wm * 32 + t * 16 + low;
                af[t] = *(const bf16x8*)(&As[ra * 64 + ((kh * 4 + quad) ^ (ra & 7)) * 8]);
                const int rb = wn * 32 + t * 16 + low;
                bfv[t] = *(const bf16x8*)(&Ws[rb * 64 + ((kh * 4 + quad) ^ (rb & 7)) * 8]);
            }
#pragma unroll
            for (int mt = 0; mt < 2; ++mt)
#pragma unroll
                for (int nt = 0; nt < 2; ++nt)
                    acc[mt][nt] = __builtin_amdgcn_mfma_f32_16x16x32_bf16(af[mt], bfv[nt], acc[mt][nt], 0, 0, 0);
        }
        k0 = kn;
        if (k0 >= K) break;
    }

#pragma unroll
    for (int nt = 0; nt < 2; ++nt) {
        const int col = c0 + wn * 32 + nt * 16 + low;
        const float bv = bias[col];
#pragma unroll
        for (int mt = 0; mt < 2; ++mt) {
            const size_t rbase = (size_t)(r0 + wm * 32 + mt * 16 + quad * 4);
#pragma unroll
            for (int r = 0; r < 4; ++r)
                out[(rbase + r) * Ccols + col] = f2bf((acc[mt][nt][r] + bv) * scale);
        }
    }
}

// ---------------------------------------------------------------------------
// o-GEMM with fused split-K combine: A[r][e] = (num1[r][e]+num2[r][e]) /
// (l1[r][h]+l2[r][h]) where h = e/64; BK=64 aligns with head boundary.
// ---------------------------------------------------------------------------
__global__ __launch_bounds__(256) void gemm64_ocomb(
    const short* __restrict__ num, const float* __restrict__ lbuf,
    const float* __restrict__ W, const float* __restrict__ bias,
    float* __restrict__ out)
{
    const int K = 512, Ccols = 256;
    const size_t NHALF = (size_t)ROWS * 512;
    const int R8 = ROWS * 8;
    __shared__ short As[64 * 64];
    __shared__ short Ws[64 * 64];
    const int tid = threadIdx.x;
    const int w = tid >> 6, lane = tid & 63, low = lane & 15, quad = lane >> 4;
    const int wm = w >> 1, wn = w & 1;
    const int r0 = blockIdx.y * 64, c0 = blockIdx.x * 64;
    const int srow = tid >> 2;
    const int sc = (tid & 3) * 2;

    f32x4 acc[2][2];
#pragma unroll
    for (int mt = 0; mt < 2; ++mt)
#pragma unroll
        for (int nt = 0; nt < 2; ++nt) acc[mt][nt] = (f32x4){0.f, 0.f, 0.f, 0.f};

    uint4 pa1[2], pa2[2];
    float pinv;
    float4 pwf[2][2];

    auto loadA = [&](int k0) {
        const int hh = k0 >> 6;
        const int row = r0 + srow;
        pinv = lbuf[row * 8 + hh] + lbuf[R8 + row * 8 + hh];
        const short* p1 = num + (size_t)row * 512 + k0 + sc * 8;
        pa1[0] = ((const uint4*)p1)[0];
        pa1[1] = ((const uint4*)p1)[1];
        const short* p2 = p1 + NHALF;
        pa2[0] = ((const uint4*)p2)[0];
        pa2[1] = ((const uint4*)p2)[1];
    };
    auto loadW = [&](int k0) {
        const float* p = W + (size_t)(c0 + srow) * K + k0 + sc * 8;
        pwf[0][0] = ((const float4*)p)[0]; pwf[0][1] = ((const float4*)p)[1];
        pwf[1][0] = ((const float4*)p)[2]; pwf[1][1] = ((const float4*)p)[3];
    };

    loadA(0); loadW(0);

    int k0 = 0;
    for (;;) {
        __syncthreads();
        {
            const float inv = 1.f / pinv;
#pragma unroll
            for (int c = 0; c < 2; ++c) {
                const int pc = (sc + c) ^ (srow & 7);
                union { unsigned u[4]; bf16x8 v; } r;
                r.u[0] = comb2(pa1[c].x, pa2[c].x, inv);
                r.u[1] = comb2(pa1[c].y, pa2[c].y, inv);
                r.u[2] = comb2(pa1[c].z, pa2[c].z, inv);
                r.u[3] = comb2(pa1[c].w, pa2[c].w, inv);
                *(bf16x8*)(&As[srow * 64 + pc * 8]) = r.v;
                *(bf16x8*)(&Ws[srow * 64 + pc * 8]) = pack8(pwf[c][0], pwf[c][1]);
            }
        }
        __syncthreads();
        const int kn = k0 + 64;
        if (kn < K) { loadA(kn); loadW(kn); }
#pragma unroll
        for (int kh = 0; kh < 2; ++kh) {
            bf16x8 af[2], bfv[2];
#pragma unroll
            for (int t = 0; t < 2; ++t) {
                const int ra = wm * 32 + t * 16 + low;
                af[t] = *(const bf16x8*)(&As[ra * 64 + ((kh * 4 + quad) ^ (ra & 7)) * 8]);
                const int rb = wn * 32 + t * 16 + low;
                bfv[t] = *(const bf16x8*)(&Ws[rb * 64 + ((kh * 4 + quad) ^ (rb & 7)) * 8]);
            }
#pragma unroll
            for (int mt = 0; mt < 2; ++mt)
#pragma unroll
                for (int nt = 0; nt < 2; ++nt)
                    acc[mt][nt] = __builtin_amdgcn_mfma_f32_16x16x32_bf16(af[mt], bfv[nt], acc[mt][nt], 0, 0, 0);
        }
        k0 = kn;
        if (k0 >= K) break;
    }

#pragma unroll
    for (int nt = 0; nt < 2; ++nt) {
        const int col = c0 + wn * 32 + nt * 16 + low;
        const float bv = bias[col];
#pragma unroll
        for (int mt = 0; mt < 2; ++mt) {
            const size_t rbase = (size_t)(r0 + wm * 32 + mt * 16 + quad * 4);
#pragma unroll
            for (int r = 0; r < 4; ++r)
                out[(rbase + r) * Ccols + col] = acc[mt][nt][r] + bv;
        }
    }
}

// ---------------------------------------------------------------------------
// MFMA flash attention on 32x32x16 bf16 (2x FLOP per LDS byte vs 16x16x32).
// Block: 256 thr = 4 waves; 128 queries/block (wave w owns queries w*32..+31);
// split-K over keys (2 halves of 16 j-tiles); XCD-swizzled 1-D grid.
// Layouts (32x32x16, verified m74/m101 C; A/B by the standard gfx950 pattern):
//   A: A[m = lane&31][k = (lane>>5)*8 + j]
//   B: B[k = (lane>>5)*8 + j][n = lane&31]
//   C: col(n) = lane&31, row(m) = (reg&3) + 8*(reg>>2) + 4*(lane>>5)
// S^T = K Q^T: A = K rows from Ks[key][dim] (stride 72), B = Q in registers
//   -> C col = query, rows = keys; lsum is scalar per lane (+1 shfl_xor(32)).
// P -> per-wave Ps[query][key] (stride 72): reg-quads = 4 consecutive keys
//   -> b64 stores.
// O = P V: A = P from Ps (b128), B = V from Vt[dim][key] (stride 72, b128)
//   -> C col = dim, rows = queries; coalesced unnormalized stores (split-K).
// ---------------------------------------------------------------------------
#define KST 72
#define VST 72
#define PST 72

__global__ __launch_bounds__(256) void attn_mfma(
    const short* __restrict__ q2,   // ROWS x 512 bf16 (pre-scaled)
    const short* __restrict__ kv2,  // ROWS x 1024 bf16
    short* __restrict__ numb,       // 2 x ROWS x 512 bf16 (unnormalized O)
    float* __restrict__ lbuf)       // 2 x ROWS x 8 fp32
{
    __shared__ short Ks[64 * KST];
    __shared__ short Vt[64 * VST];
    __shared__ short Ps[4][32 * PST];

    const int tid = threadIdx.x;
    const int w = tid >> 6;
    const int lane = tid & 63;
    const int l31 = lane & 31;
    const int h2 = lane >> 5;

    // XCD swizzle decode
    const int flat = blockIdx.x;
    const int h = flat & 7;
    const int rest = flat >> 3;
    const int half = rest & 1;
    const int rest2 = rest >> 1;
    const int qtile = rest2 & 15;
    const int b = rest2 >> 4;
    const int iq0 = qtile * 128;
    const int jt0 = half * 16;

    // --- Q fragments: B operand, 4 k-steps, registers all kernel ---
    bf16x8 qr[4];
#pragma unroll
    for (int st = 0; st < 4; ++st)
        qr[st] = *(const bf16x8*)(q2 + (size_t)(b * SEQ + iq0 + w * 32 + l31) * 512
                                  + h * 64 + st * 16 + h2 * 8);

    const short* kbase = kv2 + (size_t)(b * SEQ) * 1024 + h * 64;
    const short* vbase = kbase + 512;
    short* pw = &Ps[w][0];

    float lsum = 0.f;                 // partial: query = l31, keys of this lane
    f32x16 oacc[2];                   // [dg]; col = dim, rows = queries
#pragma unroll
    for (int dg = 0; dg < 2; ++dg)
#pragma unroll
        for (int r = 0; r < 16; ++r) oacc[dg][r] = 0.f;

    // staging indices (same as R7)
    const int krow = tid >> 2;          // key row 0..63
    const int kc = (tid & 3) * 16;      // dim chunk (shorts)
    const int vk4 = (tid & 15) * 4;     // key base (V^T)
    const int vd4 = (tid >> 4) * 4;     // dim base 0..60

    // --- prefetch first tile of this half ---
    bf16x8 pk0, pk1;
    bf16x4 pv0, pv1, pv2, pv3;
    {
        const short* ksrc = kbase + (size_t)(jt0 * 64 + krow) * 1024 + kc;
        pk0 = *(const bf16x8*)(ksrc);
        pk1 = *(const bf16x8*)(ksrc + 8);
        const short* vs = vbase + (size_t)(jt0 * 64 + vk4) * 1024 + vd4;
        pv0 = *(const bf16x4*)(vs);
        pv1 = *(const bf16x4*)(vs + 1024);
        pv2 = *(const bf16x4*)(vs + 2048);
        pv3 = *(const bf16x4*)(vs + 3072);
    }

    for (int jt = jt0; jt < jt0 + 16; ++jt) {
        __syncthreads();
        *(bf16x8*)(&Ks[krow * KST + kc]) = pk0;
        *(bf16x8*)(&Ks[krow * KST + kc + 8]) = pk1;
        {
            bf16x4 c0_, c1_, c2_, c3_;
            c0_[0] = pv0[0]; c0_[1] = pv1[0]; c0_[2] = pv2[0]; c0_[3] = pv3[0];
            c1_[0] = pv0[1]; c1_[1] = pv1[1]; c1_[2] = pv2[1]; c1_[3] = pv3[1];
            c2_[0] = pv0[2]; c2_[1] = pv1[2]; c2_[2] = pv2[2]; c2_[3] = pv3[2];
            c3_[0] = pv0[3]; c3_[1] = pv1[3]; c3_[2] = pv2[3]; c3_[3] = pv3[3];
            *(bf16x4*)(&Vt[(vd4 + 0) * VST + vk4]) = c0_;
            *(bf16x4*)(&Vt[(vd4 + 1) * VST + vk4]) = c1_;
            *(bf16x4*)(&Vt[(vd4 + 2) * VST + vk4]) = c2_;
            *(bf16x4*)(&Vt[(vd4 + 3) * VST + vk4]) = c3_;
        }
        __syncthreads();

        // prefetch next tile
        if (jt + 1 < jt0 + 16) {
            const short* ksrc = kbase + (size_t)((jt + 1) * 64 + krow) * 1024 + kc;
            pk0 = *(const bf16x8*)(ksrc);
            pk1 = *(const bf16x8*)(ksrc + 8);
            const short* vs = vbase + (size_t)((jt + 1) * 64 + vk4) * 1024 + vd4;
            pv0 = *(const bf16x4*)(vs);
            pv1 = *(const bf16x4*)(vs + 1024);
            pv2 = *(const bf16x4*)(vs + 2048);
            pv3 = *(const bf16x4*)(vs + 3072);
        }

        // --- S^T = K Q^T (2 key-groups x 4 k-steps), P = exp2, b64 stores ---
#pragma unroll
        for (int kg = 0; kg < 2; ++kg) {
            f32x16 s;
#pragma unroll
            for (int r = 0; r < 16; ++r) s[r] = 0.f;
#pragma unroll
            for (int st = 0; st < 4; ++st) {
                const bf16x8 kf = *(const bf16x8*)(&Ks[(kg * 32 + l31) * KST + st * 16 + h2 * 8]);
                s = __builtin_amdgcn_mfma_f32_32x32x16_bf16(kf, qr[st], s, 0, 0, 0);
            }
#pragma unroll
            for (int g = 0; g < 4; ++g) {
                const float p0 = __builtin_amdgcn_exp2f(s[4 * g + 0]);
                const float p1 = __builtin_amdgcn_exp2f(s[4 * g + 1]);
                const float p2 = __builtin_amdgcn_exp2f(s[4 * g + 2]);
                const float p3 = __builtin_amdgcn_exp2f(s[4 * g + 3]);
                lsum += (p0 + p1) + (p2 + p3);
                uint2 u;
                u.x = pack2bf(p0, p1);
                u.y = pack2bf(p2, p3);
                // keys kg*32 + 8*g + 4*h2 + {0..3}, query l31
                *(uint2*)(&pw[l31 * PST + kg * 32 + 8 * g + 4 * h2]) = u;
            }
        }
        __builtin_amdgcn_wave_barrier();

        // --- O += P V (4 k-steps x 2 dim-groups) ---
#pragma unroll
        for (int st = 0; st < 4; ++st) {
            const bf16x8 pf = *(const bf16x8*)(&pw[l31 * PST + st * 16 + h2 * 8]);
#pragma unroll
            for (int dg = 0; dg < 2; ++dg) {
                const bf16x8 vf = *(const bf16x8*)(&Vt[(dg * 32 + l31) * VST + st * 16 + h2 * 8]);
                oacc[dg] = __builtin_amdgcn_mfma_f32_32x32x16_bf16(pf, vf, oacc[dg], 0, 0, 0);
            }
        }
        __builtin_amdgcn_wave_barrier();
    }

    // --- epilogue: combine h2 halves of lsum; store partial l and O ---
    lsum += __shfl_xor(lsum, 32);     // all 64 keys for query = w*32 + l31
    short* nb = numb + (size_t)half * ROWS * 512;
    float* lb = lbuf + (size_t)half * ROWS * 8;
    if (lane < 32)
        lb[(size_t)(b * SEQ + iq0 + w * 32 + l31) * 8 + h] = lsum;
#pragma unroll
    for (int dg = 0; dg < 2; ++dg)
#pragma unroll
        for (int r = 0; r < 16; ++r) {
            const int qrow = w * 32 + (r & 3) + 8 * (r >> 2) + 4 * h2;
            nb[(size_t)(b * SEQ + iq0 + qrow) * 512 + h * 64 + dg * 32 + l31] =
                f2bf(oacc[dg][r]);
        }
}

// ---------------------------------------------------------------------------
extern "C" void kernel_launch(void* const* d_in, const int* in_sizes, int n_in,
                              void* d_out, int out_size, void* d_ws, size_t ws_size,
                              hipStream_t stream) {
    const float* x   = (const float*)d_in[0];  // (4,2048,256)
    const float* ctx = (const float*)d_in[1];  // (4,2048,256)
    const float* Wq  = (const float*)d_in[2];  // (512,256)
    const float* bq  = (const float*)d_in[3];
    const float* Wkv = (const float*)d_in[4];  // (1024,256)
    const float* bkv = (const float*)d_in[5];
    const float* Wo  = (const float*)d_in[6];  // (256,512)
    const float* bo  = (const float*)d_in[7];
    float* out = (float*)d_out;                // (4,2048,256) fp32

    short* xb   = (short*)d_ws;                         // ROWS*256
    short* cb   = xb + (size_t)ROWS * 256;              // ROWS*256
    short* q2b  = cb + (size_t)ROWS * 256;              // ROWS*512
    short* kv2b = q2b + (size_t)ROWS * 512;             // ROWS*1024
    short* numb = kv2b + (size_t)ROWS * 1024;           // 2*ROWS*512
    float* lbuf = (float*)(numb + (size_t)2 * ROWS * 512); // 2*ROWS*8

    const float qscale = 0.125f * 1.44269504088896f;   // softmax scale + log2e

    cvt_xc<<<4096, 256, 0, stream>>>(x, ctx, xb, cb);

    // q = x*Wq^T + bq (scaled)
    gemm64_q<<<dim3(512 / 64, ROWS / 64), 256, 0, stream>>>(
        xb, Wq, bq, q2b, 256, 512, qscale);
    // kv = ctx*Wkv^T + bkv
    gemm128<true><<<dim3(1024 / 128, ROWS / 128), 256, 0, stream>>>(
        cb, Wkv, bkv, kv2b, 256, 1024, 1.0f);
    // attention, split-K x2, 32x32x16 MFMA, XCD-swizzled 1-D grid (1024 blocks)
    attn_mfma<<<NB * NHEADS * (SEQ / 128) * 2, 256, 0, stream>>>(
        q2b, kv2b, numb, lbuf);
    // out = combine(num1,num2)/(l1+l2) * Wo^T + bo
    gemm64_ocomb<<<dim3(256 / 64, ROWS / 64), 256, 0, stream>>>(
        numb, lbuf, Wo, bo, out);
}